// Round 3
// baseline (59.415 us; speedup 1.0000x reference)
//
#include <hip/hip_runtime.h>

// MinibatchDiscrimination — all-pairs L1 distance + concat.
//   inputs: [N=1024, D=512] fp32
//   out[i, 0:512]   = inputs[i, :]
//   out[i, 512 + j] = sum_d |x[i,d] - x[j,d]|
// out is [1024, 1536] fp32 row-major.
//
// R3 design: 64x64 tile, 512 threads (8 waves, 2/SIMD), grid 16x16=256.
//   - Each wave owns 8 A-rows (wave-uniform) -> A streamed via the SCALAR
//     pipe (s_load_dwordx4): no LDS, no VALU, no vector-VMEM cost.
//   - B tile staged once in LDS row-major [64][516] (129 KB), full k-range;
//     lane j reads its row as one ds_read_b128 per 4 k's.
//   - micro-tile 8x1 per thread -> 64 VALU (32 sub + 32 add-abs) per 4k.
// Per-CU budget: VALU 13.65us (floor), LDS ~5us, scalar/L2 ~1us -> VALU-bound.

#define N_PTS 1024
#define D_DIM 512
#define OUTW  (D_DIM + N_PTS)   // 1536
#define BT    64                 // tile side (i and j)
#define BSTR  516                // Bs row stride in floats (mod 32 = 4 -> banks spread)

// -------- copy inputs into out[:, 0:D] ------------------------------------
__global__ __launch_bounds__(256) void copy_rows_kernel(const float* __restrict__ x,
                                                        float* __restrict__ out) {
    int idx = blockIdx.x * blockDim.x + threadIdx.x;   // 0 .. N*D/4-1
    int i = idx >> 7;          // D/4 = 128 float4 per row
    int d = idx & 127;
    *(float4*)&out[(size_t)i * OUTW + (d << 2)] =
        *(const float4*)&x[(size_t)i * D_DIM + (d << 2)];
}

// -------- all-pairs L1: scalar-A / LDS-B ----------------------------------
__global__ __launch_bounds__(512, 2) void l1_pairs_kernel(const float* __restrict__ x,
                                                          float* __restrict__ out) {
    __shared__ __align__(16) float Bs[BT * BSTR];   // 64 x 516 floats = 129 KB

    const int t    = threadIdx.x;
    const int rowA = blockIdx.y * BT;
    const int colB = blockIdx.x * BT;

    // ---- stage B tile rows colB..+63, all 512 k, row-major ----
    {
        const int j  = t >> 3;          // 0..63, 8 threads per row
        const int kc = t & 7;           // float4 phase within row
        const float* src = x  + (size_t)(colB + j) * D_DIM;
        float*       dst = Bs + j * BSTR;
        #pragma unroll
        for (int c = 0; c < 16; ++c) {
            const int k4 = kc + c * 8;                  // float4 index 0..127
            *(float4*)(dst + 4 * k4) = *(const float4*)(src + 4 * k4);
        }
    }
    __syncthreads();

    const int lane = t & 63;                                  // j within tile
    const int w    = __builtin_amdgcn_readfirstlane(t >> 6);  // wave 0..7 (SGPR)
    const float* xa = x  + (size_t)(rowA + w * 8) * D_DIM;    // wave-uniform base
    const float* bp = Bs + lane * BSTR;                       // per-lane B row

    float acc[8] = {0.f, 0.f, 0.f, 0.f, 0.f, 0.f, 0.f, 0.f};

    #pragma unroll 2
    for (int k4 = 0; k4 < 128; ++k4) {
        const float4 b = *(const float4*)(bp + 4 * k4);       // ds_read_b128
        #pragma unroll
        for (int r = 0; r < 8; ++r) {
            // uniform address -> s_load_dwordx4 (scalar pipe)
            const float4 a = *(const float4*)(xa + r * D_DIM + 4 * k4);
            acc[r] += fabsf(a.x - b.x);
            acc[r] += fabsf(a.y - b.y);
            acc[r] += fabsf(a.z - b.z);
            acc[r] += fabsf(a.w - b.w);
        }
    }

    #pragma unroll
    for (int r = 0; r < 8; ++r)
        out[(size_t)(rowA + w * 8 + r) * OUTW + D_DIM + colB + lane] = acc[r];
}

extern "C" void kernel_launch(void* const* d_in, const int* in_sizes, int n_in,
                              void* d_out, int out_size, void* d_ws, size_t ws_size,
                              hipStream_t stream) {
    const float* x   = (const float*)d_in[0];
    float*       out = (float*)d_out;

    hipLaunchKernelGGL(copy_rows_kernel, dim3((N_PTS * D_DIM / 4) / 256), dim3(256),
                       0, stream, x, out);

    hipLaunchKernelGGL(l1_pairs_kernel, dim3(N_PTS / BT, N_PTS / BT), dim3(512),
                       0, stream, x, out);
}